// Round 5
// baseline (275.324 us; speedup 1.0000x reference)
//
#include <hip/hip_runtime.h>

// Problem constants (from reference): B=8, N=256, F_IN=F_OUT=64, all fp32 I/O.
#define NN    256
#define FF    64
#define BROWS 2048            // B*N
#define W_ELEMS 33554432      // 8*256*256*64

typedef float v4f __attribute__((ext_vector_type(4)));

// ---------------------------------------------------------------------------
// Kernel 1: both MLPs (n_func and s_func) in fp32, outputs to workspace.
// One block (64 threads) per (b,i) row.  (~5 us total; not the bottleneck.)
// ---------------------------------------------------------------------------
__global__ __launch_bounds__(64) void mlp_kernel(
    const float* __restrict__ x,
    const float* __restrict__ nw1, const float* __restrict__ nb1,
    const float* __restrict__ nw2, const float* __restrict__ nb2,
    const float* __restrict__ sw1, const float* __restrict__ sb1,
    const float* __restrict__ sw2, const float* __restrict__ sb2,
    float* __restrict__ x1, float* __restrict__ sout)
{
    const int row = blockIdx.x;      // b*N + i
    const int e   = threadIdx.x;     // 0..63

    __shared__ float xr[FF];
    __shared__ float h[FF];

    xr[e] = x[row * FF + e];
    __syncthreads();

    float acc = nb1[e];
#pragma unroll
    for (int k = 0; k < FF; ++k) acc = fmaf(xr[k], nw1[k * FF + e], acc);
    h[e] = fmaxf(acc, 0.0f);
    __syncthreads();

    acc = nb2[e];
#pragma unroll
    for (int k = 0; k < FF; ++k) acc = fmaf(h[k], nw2[k * FF + e], acc);
    x1[row * FF + e] = fmaxf(acc, 0.0f);
    __syncthreads();

    acc = sb1[e];
#pragma unroll
    for (int k = 0; k < FF; ++k) acc = fmaf(xr[k], sw1[k * FF + e], acc);
    h[e] = fmaxf(acc, 0.0f);
    __syncthreads();

    acc = sb2[e];
#pragma unroll
    for (int k = 0; k < FF; ++k) acc = fmaf(h[k], sw2[k * FF + e], acc);
    sout[row * FF + e] = fmaxf(acc, 0.0f);
}

// ---------------------------------------------------------------------------
// Kernel 2 (v3): aggregation ONLY — no W passthrough store.
//   x2[e] = sum_j An[j]*W[j,e]*x1[b,j,e] + sout[e]
// W loads are TEMPORAL so the 134 MB W stream is inserted into L2/L3;
// the following copy kernel then reads W from Infinity Cache, not HBM.
// Pure read-stream -> should run near the 6.3-6.8 TB/s single-direction rate.
// __launch_bounds__(256,8): cap VGPR at 64 -> 32 waves/CU for TLP.
// Thread = (jg = tid>>4, fc = tid&15); chunk ci = c*256 + tid == j*16 + fc.
// ---------------------------------------------------------------------------
__global__ __launch_bounds__(256, 8) void agg_kernel(
    const float* __restrict__ A, const float* __restrict__ W,
    const float* __restrict__ x1, const float* __restrict__ sout,
    float* __restrict__ outx2)
{
    const int row = blockIdx.x;      // b*N + i
    const int b   = row >> 8;        // N = 256
    const int tid = threadIdx.x;

    __shared__ float an[NN];
    __shared__ float partial[4];
    __shared__ float red[256][4];

    // ---- L1 row normalization of A ----
    const float a = A[row * NN + tid];
    float s = fabsf(a);
#pragma unroll
    for (int off = 32; off > 0; off >>= 1) s += __shfl_down(s, off, 64);
    if ((tid & 63) == 0) partial[tid >> 6] = s;
    __syncthreads();
    const float denom = fmaxf(partial[0] + partial[1] + partial[2] + partial[3], 1e-12f);
    an[tid] = a / denom;
    __syncthreads();

    // ---- stream W row (read-only) + weighted aggregation ----
    const v4f* __restrict__ Wrow = (const v4f*)(W + (size_t)row * (NN * FF));
    const v4f* __restrict__ x1b  = (const v4f*)(x1 + b * (NN * FF));

    const int jg = tid >> 4;     // j-subgroup 0..15

    float acc0 = 0.0f, acc1 = 0.0f, acc2 = 0.0f, acc3 = 0.0f;

    // Groups of 2 chunks, depth-2 pipeline: 8 v4f in flight (~50 VGPR total).
#define LOADG(wp, xp, cbase)                                                  \
    _Pragma("unroll")                                                         \
    for (int q = 0; q < 2; ++q) {                                             \
        wp[q] = Wrow[(cbase) + q * 256 + tid];                                \
        xp[q] = x1b[(cbase) + q * 256 + tid];                                 \
    }

#define USEG(wp, xp, jjb)                                                     \
    _Pragma("unroll")                                                         \
    for (int q = 0; q < 2; ++q) {                                             \
        const float av = an[((jjb) + q) * 16 + jg];                           \
        acc0 = fmaf(av * wp[q].x, xp[q].x, acc0);                             \
        acc1 = fmaf(av * wp[q].y, xp[q].y, acc1);                             \
        acc2 = fmaf(av * wp[q].z, xp[q].z, acc2);                             \
        acc3 = fmaf(av * wp[q].w, xp[q].w, acc3);                             \
    }

    v4f wA[2], xA[2], wB[2], xB[2];

    LOADG(wA, xA, 0)
    LOADG(wB, xB, 512)
    USEG (wA, xA, 0)   LOADG(wA, xA, 1024)
    USEG (wB, xB, 2)   LOADG(wB, xB, 1536)
    USEG (wA, xA, 4)   LOADG(wA, xA, 2048)
    USEG (wB, xB, 6)   LOADG(wB, xB, 2560)
    USEG (wA, xA, 8)   LOADG(wA, xA, 3072)
    USEG (wB, xB, 10)  LOADG(wB, xB, 3584)
    USEG (wA, xA, 12)
    USEG (wB, xB, 14)

#undef LOADG
#undef USEG

    // ---- reduce over the 16 j-groups ----
    red[tid][0] = acc0; red[tid][1] = acc1;
    red[tid][2] = acc2; red[tid][3] = acc3;
    __syncthreads();

    if (tid < 64) {
        const int c = tid >> 2;      // feature quad
        const int r = tid & 3;       // feature = c*4+r = tid
        float sum = 0.0f;
#pragma unroll
        for (int g = 0; g < 16; ++g) sum += red[g * 16 + c][r];  // 2-way bank alias, free
        sum += sout[row * FF + tid];
        outx2[row * FF + tid] = sum;
    }
}

// ---------------------------------------------------------------------------
// Kernel 3 (v3): pure copy W -> outW.  One block per W row (64 KB).
// TEMPORAL loads: hit the L3 lines inserted by agg_kernel (W = 134 MB fits
// the 256 MiB Infinity Cache).  NONTEMPORAL stores: outW is never re-read
// and must not evict the not-yet-copied W lines from L3.
// 8 loads batched before 8 stores -> 8 outstanding loads/wave, ~40 VGPR,
// 32 waves/CU.  This is the proven m13 copy pattern (6.29 TB/s).
// ---------------------------------------------------------------------------
__global__ __launch_bounds__(256) void copyw_kernel(
    const float* __restrict__ src, float* __restrict__ dst)
{
    const v4f* __restrict__ s = (const v4f*)src;
    v4f*       __restrict__ d = (v4f*)dst;
    const int base = blockIdx.x * 4096 + threadIdx.x;   // 4096 v4f per block

    v4f t[8];
#pragma unroll
    for (int h = 0; h < 2; ++h) {
#pragma unroll
        for (int k = 0; k < 8; ++k)
            t[k] = s[base + (h * 8 + k) * 256];
#pragma unroll
        for (int k = 0; k < 8; ++k)
            __builtin_nontemporal_store(t[k], d + base + (h * 8 + k) * 256);
    }
}

extern "C" void kernel_launch(void* const* d_in, const int* in_sizes, int n_in,
                              void* d_out, int out_size, void* d_ws, size_t ws_size,
                              hipStream_t stream) {
    const float* A   = (const float*)d_in[0];
    const float* W   = (const float*)d_in[1];
    const float* x   = (const float*)d_in[2];
    const float* nw1 = (const float*)d_in[3];
    const float* nb1 = (const float*)d_in[4];
    const float* nw2 = (const float*)d_in[5];
    const float* nb2 = (const float*)d_in[6];
    const float* sw1 = (const float*)d_in[7];
    const float* sb1 = (const float*)d_in[8];
    const float* sw2 = (const float*)d_in[9];
    const float* sb2 = (const float*)d_in[10];

    float* x1 = (float*)d_ws;                  // 2048*64 fp32 = 512 KB
    float* so = x1 + BROWS * FF;               // + 512 KB

    float* outW  = (float*)d_out;
    float* outx2 = outW + W_ELEMS;

    mlp_kernel<<<BROWS, 64, 0, stream>>>(x, nw1, nb1, nw2, nb2,
                                         sw1, sb1, sw2, sb2, x1, so);
    // agg first: temporal W reads warm L3 for the copy.
    agg_kernel<<<BROWS, 256, 0, stream>>>(A, W, x1, so, outx2);
    copyw_kernel<<<BROWS, 256, 0, stream>>>(W, outW);
}

// Round 6
// 257.857 us; speedup vs baseline: 1.0677x; 1.0677x over previous
//
#include <hip/hip_runtime.h>

// Problem constants (from reference): B=8, N=256, F_IN=F_OUT=64, all fp32 I/O.
#define NN    256
#define FF    64
#define BROWS 2048            // B*N
#define W_ELEMS 33554432      // 8*256*256*64

typedef float v4f __attribute__((ext_vector_type(4)));

// ---------------------------------------------------------------------------
// Kernel 1: both MLPs (n_func and s_func) in fp32, outputs to workspace.
// One block (64 threads) per (b,i) row.  (~5 us total; not the bottleneck.)
// ---------------------------------------------------------------------------
__global__ __launch_bounds__(64) void mlp_kernel(
    const float* __restrict__ x,
    const float* __restrict__ nw1, const float* __restrict__ nb1,
    const float* __restrict__ nw2, const float* __restrict__ nb2,
    const float* __restrict__ sw1, const float* __restrict__ sb1,
    const float* __restrict__ sw2, const float* __restrict__ sb2,
    float* __restrict__ x1, float* __restrict__ sout)
{
    const int row = blockIdx.x;      // b*N + i
    const int e   = threadIdx.x;     // 0..63

    __shared__ float xr[FF];
    __shared__ float h[FF];

    xr[e] = x[row * FF + e];
    __syncthreads();

    float acc = nb1[e];
#pragma unroll
    for (int k = 0; k < FF; ++k) acc = fmaf(xr[k], nw1[k * FF + e], acc);
    h[e] = fmaxf(acc, 0.0f);
    __syncthreads();

    acc = nb2[e];
#pragma unroll
    for (int k = 0; k < FF; ++k) acc = fmaf(h[k], nw2[k * FF + e], acc);
    x1[row * FF + e] = fmaxf(acc, 0.0f);
    __syncthreads();

    acc = sb1[e];
#pragma unroll
    for (int k = 0; k < FF; ++k) acc = fmaf(xr[k], sw1[k * FF + e], acc);
    h[e] = fmaxf(acc, 0.0f);
    __syncthreads();

    acc = sb2[e];
#pragma unroll
    for (int k = 0; k < FF; ++k) acc = fmaf(h[k], sw2[k * FF + e], acc);
    sout[row * FF + e] = fmaxf(acc, 0.0f);
}

// ---------------------------------------------------------------------------
// Kernel 2 (v4): FUSED stream — outW copy + weighted aggregation in one pass
// (round-5 split proved L3 does not retain W across dispatches: +22 us).
//   outW = W, x2[e] = sum_j An[j]*W[j,e]*x1[b,j,e] + sout[e]
//
// v4 vs v2.1(R4, 253us): occupancy over per-wave ILP.
//   * 2-chunk groups, depth-2 pipeline: only 8 v4f live -> ~55 VGPR.
//   * __launch_bounds__(256,8): <=64 VGPR -> 8 waves/SIMD, 32 waves/CU.
//     (the 6.8 TB/s fill kernel proves peak BW comes from TLP at tiny VGPR,
//      not from deep per-wave pipelines: 8 VGPR, 9.5% occupancy.)
//   * NT W loads + NT outW stores (zero-reuse stream, protect L2 x1).
// Thread = (jg = tid>>4, fc = tid&15); chunk ci = jj*256 + tid == j*16 + fc
// -> coalesced 16 B/lane; same index addresses x1's float4 for (j, fc).
// ---------------------------------------------------------------------------
__global__ __launch_bounds__(256, 8) void agg_kernel(
    const float* __restrict__ A, const float* __restrict__ W,
    const float* __restrict__ x1, const float* __restrict__ sout,
    float* __restrict__ outW, float* __restrict__ outx2)
{
    const int row = blockIdx.x;      // b*N + i
    const int b   = row >> 8;        // N = 256
    const int tid = threadIdx.x;

    __shared__ float an[NN];
    __shared__ float partial[4];
    __shared__ float red[256][4];

    // ---- L1 row normalization of A ----
    const float a = A[row * NN + tid];
    float s = fabsf(a);
#pragma unroll
    for (int off = 32; off > 0; off >>= 1) s += __shfl_down(s, off, 64);
    if ((tid & 63) == 0) partial[tid >> 6] = s;
    __syncthreads();
    const float denom = fmaxf(partial[0] + partial[1] + partial[2] + partial[3], 1e-12f);
    an[tid] = a / denom;
    __syncthreads();

    // ---- fused stream: W -> outW copy + weighted aggregation ----
    const v4f* __restrict__ Wrow = (const v4f*)(W + (size_t)row * (NN * FF));
    v4f* __restrict__ Orow       = (v4f*)(outW + (size_t)row * (NN * FF));
    const v4f* __restrict__ x1b  = (const v4f*)(x1 + b * (NN * FF));

    const int jg = tid >> 4;     // j-subgroup 0..15

    float acc0 = 0.0f, acc1 = 0.0f, acc2 = 0.0f, acc3 = 0.0f;

    // Group = 2 chunks (cbase in v4f units; jjb = cbase/256).
#define LOADG(wp, xp, cbase)                                                  \
    _Pragma("unroll")                                                         \
    for (int q = 0; q < 2; ++q) {                                             \
        wp[q] = __builtin_nontemporal_load(Wrow + (cbase) + q * 256 + tid);   \
        xp[q] = x1b[(cbase) + q * 256 + tid];                                 \
    }

#define USEG(wp, xp, cbase, jjb)                                              \
    _Pragma("unroll")                                                         \
    for (int q = 0; q < 2; ++q) {                                             \
        __builtin_nontemporal_store(wp[q], Orow + (cbase) + q * 256 + tid);   \
    }                                                                         \
    _Pragma("unroll")                                                         \
    for (int q = 0; q < 2; ++q) {                                             \
        const float av = an[((jjb) + q) * 16 + jg];                           \
        acc0 = fmaf(av * wp[q].x, xp[q].x, acc0);                             \
        acc1 = fmaf(av * wp[q].y, xp[q].y, acc1);                             \
        acc2 = fmaf(av * wp[q].z, xp[q].z, acc2);                             \
        acc3 = fmaf(av * wp[q].w, xp[q].w, acc3);                             \
    }

    v4f wA[2], xA[2], wB[2], xB[2];

    LOADG(wA, xA, 0)
    LOADG(wB, xB, 512)
    USEG (wA, xA, 0,    0)   LOADG(wA, xA, 1024)
    USEG (wB, xB, 512,  2)   LOADG(wB, xB, 1536)
    USEG (wA, xA, 1024, 4)   LOADG(wA, xA, 2048)
    USEG (wB, xB, 1536, 6)   LOADG(wB, xB, 2560)
    USEG (wA, xA, 2048, 8)   LOADG(wA, xA, 3072)
    USEG (wB, xB, 2560, 10)  LOADG(wB, xB, 3584)
    USEG (wA, xA, 3072, 12)
    USEG (wB, xB, 3584, 14)

#undef LOADG
#undef USEG

    // ---- reduce over the 16 j-groups ----
    red[tid][0] = acc0; red[tid][1] = acc1;
    red[tid][2] = acc2; red[tid][3] = acc3;
    __syncthreads();

    if (tid < 64) {
        const int c = tid >> 2;      // feature quad
        const int r = tid & 3;       // feature = c*4+r = tid
        float sum = 0.0f;
#pragma unroll
        for (int g = 0; g < 16; ++g) sum += red[g * 16 + c][r];  // 2-way bank alias, free
        sum += sout[row * FF + tid];
        outx2[row * FF + tid] = sum;
    }
}

extern "C" void kernel_launch(void* const* d_in, const int* in_sizes, int n_in,
                              void* d_out, int out_size, void* d_ws, size_t ws_size,
                              hipStream_t stream) {
    const float* A   = (const float*)d_in[0];
    const float* W   = (const float*)d_in[1];
    const float* x   = (const float*)d_in[2];
    const float* nw1 = (const float*)d_in[3];
    const float* nb1 = (const float*)d_in[4];
    const float* nw2 = (const float*)d_in[5];
    const float* nb2 = (const float*)d_in[6];
    const float* sw1 = (const float*)d_in[7];
    const float* sb1 = (const float*)d_in[8];
    const float* sw2 = (const float*)d_in[9];
    const float* sb2 = (const float*)d_in[10];

    float* x1 = (float*)d_ws;                  // 2048*64 fp32 = 512 KB
    float* so = x1 + BROWS * FF;               // + 512 KB

    float* outW  = (float*)d_out;
    float* outx2 = outW + W_ELEMS;

    mlp_kernel<<<BROWS, 64, 0, stream>>>(x, nw1, nb1, nw2, nb2,
                                         sw1, sb1, sw2, sb2, x1, so);
    agg_kernel<<<BROWS, 256, 0, stream>>>(A, W, x1, so, outW, outx2);
}

// Round 12
// 256.459 us; speedup vs baseline: 1.0736x; 1.0055x over previous
//
#include <hip/hip_runtime.h>

// Problem constants (from reference): B=8, N=256, F_IN=F_OUT=64, all fp32 I/O.
#define NN    256
#define FF    64
#define BROWS 2048            // B*N
#define W_ELEMS 33554432      // 8*256*256*64

typedef float v4f __attribute__((ext_vector_type(4)));

// ---------------------------------------------------------------------------
// Kernel 1: both MLPs (n_func and s_func) in fp32, outputs to workspace.
// One block (64 threads) per (b,i) row.  (~5 us total; not the bottleneck.)
// ---------------------------------------------------------------------------
__global__ __launch_bounds__(64) void mlp_kernel(
    const float* __restrict__ x,
    const float* __restrict__ nw1, const float* __restrict__ nb1,
    const float* __restrict__ nw2, const float* __restrict__ nb2,
    const float* __restrict__ sw1, const float* __restrict__ sb1,
    const float* __restrict__ sw2, const float* __restrict__ sb2,
    float* __restrict__ x1, float* __restrict__ sout)
{
    const int row = blockIdx.x;      // b*N + i
    const int e   = threadIdx.x;     // 0..63

    __shared__ float xr[FF];
    __shared__ float h[FF];

    xr[e] = x[row * FF + e];
    __syncthreads();

    float acc = nb1[e];
#pragma unroll
    for (int k = 0; k < FF; ++k) acc = fmaf(xr[k], nw1[k * FF + e], acc);
    h[e] = fmaxf(acc, 0.0f);
    __syncthreads();

    acc = nb2[e];
#pragma unroll
    for (int k = 0; k < FF; ++k) acc = fmaf(h[k], nw2[k * FF + e], acc);
    x1[row * FF + e] = fmaxf(acc, 0.0f);
    __syncthreads();

    acc = sb1[e];
#pragma unroll
    for (int k = 0; k < FF; ++k) acc = fmaf(xr[k], sw1[k * FF + e], acc);
    h[e] = fmaxf(acc, 0.0f);
    __syncthreads();

    acc = sb2[e];
#pragma unroll
    for (int k = 0; k < FF; ++k) acc = fmaf(h[k], sw2[k * FF + e], acc);
    sout[row * FF + e] = fmaxf(acc, 0.0f);
}

// ---------------------------------------------------------------------------
// Kernel 2 (v5): R4's best structure (253.1 us) with ONE change:
//   outW stores are NORMAL (writeback L2) instead of nontemporal.
// Rationale: the 6.75 TB/s fill and 6.29 TB/s copy both use normal stores;
// NT stores were never isolated and are the only unexplored memory-policy
// axis after three schedule variants all pinned at ~4 TB/s.
//   * depth-2 software pipeline over 4-chunk groups (8 loads in flight).
//   * NT W loads (zero-reuse read stream; don't pollute L2 / evict x1).
//   * __launch_bounds__(256,4): VGPR cap 128, ~16 waves/CU (best measured).
// Thread = (jg = tid>>4, fc = tid&15); chunk ci = jj*256 + tid == j*16 + fc
// -> coalesced 16 B/lane; same index addresses x1's float4 for (j, fc).
// ---------------------------------------------------------------------------
__global__ __launch_bounds__(256, 4) void agg_kernel(
    const float* __restrict__ A, const float* __restrict__ W,
    const float* __restrict__ x1, const float* __restrict__ sout,
    float* __restrict__ outW, float* __restrict__ outx2)
{
    const int row = blockIdx.x;      // b*N + i
    const int b   = row >> 8;        // N = 256
    const int tid = threadIdx.x;

    __shared__ float an[NN];
    __shared__ float partial[4];
    __shared__ float red[256][4];

    // ---- L1 row normalization of A ----
    const float a = A[row * NN + tid];
    float s = fabsf(a);
#pragma unroll
    for (int off = 32; off > 0; off >>= 1) s += __shfl_down(s, off, 64);
    if ((tid & 63) == 0) partial[tid >> 6] = s;
    __syncthreads();
    const float denom = fmaxf(partial[0] + partial[1] + partial[2] + partial[3], 1e-12f);
    an[tid] = a / denom;
    __syncthreads();

    // ---- fused stream: W -> outW copy + weighted aggregation ----
    const v4f* __restrict__ Wrow = (const v4f*)(W + (size_t)row * (NN * FF));
    v4f* __restrict__ Orow       = (v4f*)(outW + (size_t)row * (NN * FF));
    const v4f* __restrict__ x1b  = (const v4f*)(x1 + b * (NN * FF));

    const int jg = tid >> 4;     // j-subgroup 0..15

    float acc0 = 0.0f, acc1 = 0.0f, acc2 = 0.0f, acc3 = 0.0f;

    // One group = 4 consecutive jj chunks (cbase = jj*256 .. +3*256).
    // All q-indices are compile-time constants after unroll -> registers.
#define LOADG(wp, xp, cbase)                                                  \
    _Pragma("unroll")                                                         \
    for (int q = 0; q < 4; ++q) {                                             \
        wp[q] = __builtin_nontemporal_load(Wrow + (cbase) + q * 256 + tid);   \
        xp[q] = x1b[(cbase) + q * 256 + tid];                                 \
    }

#define USEG(wp, xp, cbase, jjb)                                              \
    _Pragma("unroll")                                                         \
    for (int q = 0; q < 4; ++q) {                                             \
        Orow[(cbase) + q * 256 + tid] = wp[q];   /* NORMAL store (v5) */      \
    }                                                                         \
    _Pragma("unroll")                                                         \
    for (int q = 0; q < 4; ++q) {                                             \
        const float av = an[((jjb) + q) * 16 + jg];                           \
        acc0 = fmaf(av * wp[q].x, xp[q].x, acc0);                             \
        acc1 = fmaf(av * wp[q].y, xp[q].y, acc1);                             \
        acc2 = fmaf(av * wp[q].z, xp[q].z, acc2);                             \
        acc3 = fmaf(av * wp[q].w, xp[q].w, acc3);                             \
    }

    v4f wA[4], xA[4];
    v4f wB[4], xB[4];

    LOADG(wA, xA, 0)          // group 0: jj 0..3
    LOADG(wB, xB, 1024)       // group 1: jj 4..7   (in flight behind group 0)
    USEG (wA, xA, 0, 0)
    LOADG(wA, xA, 2048)       // group 2: jj 8..11
    USEG (wB, xB, 1024, 4)
    LOADG(wB, xB, 3072)       // group 3: jj 12..15
    USEG (wA, xA, 2048, 8)
    USEG (wB, xB, 3072, 12)

#undef LOADG
#undef USEG

    // ---- reduce over the 16 j-groups ----
    red[tid][0] = acc0; red[tid][1] = acc1;
    red[tid][2] = acc2; red[tid][3] = acc3;
    __syncthreads();

    if (tid < 64) {
        const int c = tid >> 2;      // feature quad
        const int r = tid & 3;       // feature = c*4+r = tid
        float sum = 0.0f;
#pragma unroll
        for (int g = 0; g < 16; ++g) sum += red[g * 16 + c][r];  // 2-way bank alias, free
        sum += sout[row * FF + tid];
        outx2[row * FF + tid] = sum;
    }
}

extern "C" void kernel_launch(void* const* d_in, const int* in_sizes, int n_in,
                              void* d_out, int out_size, void* d_ws, size_t ws_size,
                              hipStream_t stream) {
    const float* A   = (const float*)d_in[0];
    const float* W   = (const float*)d_in[1];
    const float* x   = (const float*)d_in[2];
    const float* nw1 = (const float*)d_in[3];
    const float* nb1 = (const float*)d_in[4];
    const float* nw2 = (const float*)d_in[5];
    const float* nb2 = (const float*)d_in[6];
    const float* sw1 = (const float*)d_in[7];
    const float* sb1 = (const float*)d_in[8];
    const float* sw2 = (const float*)d_in[9];
    const float* sb2 = (const float*)d_in[10];

    float* x1 = (float*)d_ws;                  // 2048*64 fp32 = 512 KB
    float* so = x1 + BROWS * FF;               // + 512 KB

    float* outW  = (float*)d_out;
    float* outx2 = outW + W_ELEMS;

    mlp_kernel<<<BROWS, 64, 0, stream>>>(x, nw1, nb1, nw2, nb2,
                                         sw1, sb1, sw2, sb2, x1, so);
    agg_kernel<<<BROWS, 256, 0, stream>>>(A, W, x1, so, outW, outx2);
}

// Round 13
// 252.547 us; speedup vs baseline: 1.0902x; 1.0155x over previous
//
#include <hip/hip_runtime.h>

// Problem constants (from reference): B=8, N=256, F_IN=F_OUT=64, all fp32 I/O.
#define NN    256
#define FF    64
#define BROWS 2048            // B*N
#define W_ELEMS 33554432      // 8*256*256*64

typedef float v4f __attribute__((ext_vector_type(4)));

// ---------------------------------------------------------------------------
// Kernel 1: both MLPs (n_func and s_func) in fp32, outputs to workspace.
// One block (64 threads) per (b,i) row.  (~5 us total; not the bottleneck.)
// ---------------------------------------------------------------------------
__global__ __launch_bounds__(64) void mlp_kernel(
    const float* __restrict__ x,
    const float* __restrict__ nw1, const float* __restrict__ nb1,
    const float* __restrict__ nw2, const float* __restrict__ nb2,
    const float* __restrict__ sw1, const float* __restrict__ sb1,
    const float* __restrict__ sw2, const float* __restrict__ sb2,
    float* __restrict__ x1, float* __restrict__ sout)
{
    const int row = blockIdx.x;      // b*N + i
    const int e   = threadIdx.x;     // 0..63

    __shared__ float xr[FF];
    __shared__ float h[FF];

    xr[e] = x[row * FF + e];
    __syncthreads();

    float acc = nb1[e];
#pragma unroll
    for (int k = 0; k < FF; ++k) acc = fmaf(xr[k], nw1[k * FF + e], acc);
    h[e] = fmaxf(acc, 0.0f);
    __syncthreads();

    acc = nb2[e];
#pragma unroll
    for (int k = 0; k < FF; ++k) acc = fmaf(h[k], nw2[k * FF + e], acc);
    x1[row * FF + e] = fmaxf(acc, 0.0f);
    __syncthreads();

    acc = sb1[e];
#pragma unroll
    for (int k = 0; k < FF; ++k) acc = fmaf(xr[k], sw1[k * FF + e], acc);
    h[e] = fmaxf(acc, 0.0f);
    __syncthreads();

    acc = sb2[e];
#pragma unroll
    for (int k = 0; k < FF; ++k) acc = fmaf(h[k], sw2[k * FF + e], acc);
    sout[row * FF + e] = fmaxf(acc, 0.0f);
}

// ---------------------------------------------------------------------------
// Kernel 2 (v6): R4 structure + x1 staged in LDS.
// A/B history: schedules (ILP depth, occupancy) and store policy (NT vs
// normal) are ALL neutral at ~70 us / ~3.9 TB/s.  Remaining structural
// difference vs the 6.29 TB/s copy benchmark: a SECOND global-load stream
// (x1 from L2, 134 MB logical) interleaved in the same vmem queue + L2
// read-path contention with the HBM pass-through traffic.
// v6 removes it: stage x1[b] (64 KB) into LDS once per block; hot loop
// reads x1 from LDS.  Halves vmem load instructions; zero L2 x1 traffic.
// LDS = 64K(x1s) + 4K(red) + 1K(an) ~ 69 KB -> 2 blocks/CU (BW needs ~3
// waves/CU per the fill kernel's 6.8 TB/s at 9.5% occupancy; fine).
// Stores NT (R4 flavor).  Depth-2 pipeline over 4-chunk groups.
// ---------------------------------------------------------------------------
__global__ __launch_bounds__(256, 4) void agg_kernel(
    const float* __restrict__ A, const float* __restrict__ W,
    const float* __restrict__ x1, const float* __restrict__ sout,
    float* __restrict__ outW, float* __restrict__ outx2)
{
    const int row = blockIdx.x;      // b*N + i
    const int b   = row >> 8;        // N = 256
    const int tid = threadIdx.x;

    __shared__ float an[NN];
    __shared__ float partial[4];
    __shared__ float red[256][4];
    __shared__ v4f   x1s[NN * FF / 4];    // 4096 entries = 64 KB

    // ---- stage x1[b] panel into LDS (16 coalesced L2 reads / thread) ----
    const v4f* __restrict__ x1g = (const v4f*)(x1 + b * (NN * FF));
#pragma unroll
    for (int k = 0; k < 16; ++k)
        x1s[k * 256 + tid] = x1g[k * 256 + tid];

    // ---- L1 row normalization of A ----
    const float a = A[row * NN + tid];
    float s = fabsf(a);
#pragma unroll
    for (int off = 32; off > 0; off >>= 1) s += __shfl_down(s, off, 64);
    if ((tid & 63) == 0) partial[tid >> 6] = s;
    __syncthreads();
    const float denom = fmaxf(partial[0] + partial[1] + partial[2] + partial[3], 1e-12f);
    an[tid] = a / denom;
    __syncthreads();   // an[] ready AND x1s[] staged

    // ---- fused stream: W -> outW copy + weighted aggregation ----
    const v4f* __restrict__ Wrow = (const v4f*)(W + (size_t)row * (NN * FF));
    v4f* __restrict__ Orow       = (v4f*)(outW + (size_t)row * (NN * FF));

    const int jg = tid >> 4;     // j-subgroup 0..15

    float acc0 = 0.0f, acc1 = 0.0f, acc2 = 0.0f, acc3 = 0.0f;

    // One group = 4 consecutive jj chunks (cbase = jj*256 .. +3*256).
    // W from global (NT); x1 from LDS.  All q-indices compile-time const.
#define LOADG(wp, xp, cbase)                                                  \
    _Pragma("unroll")                                                         \
    for (int q = 0; q < 4; ++q) {                                             \
        wp[q] = __builtin_nontemporal_load(Wrow + (cbase) + q * 256 + tid);   \
        xp[q] = x1s[(cbase) + q * 256 + tid];                                 \
    }

#define USEG(wp, xp, cbase, jjb)                                              \
    _Pragma("unroll")                                                         \
    for (int q = 0; q < 4; ++q) {                                             \
        __builtin_nontemporal_store(wp[q], Orow + (cbase) + q * 256 + tid);   \
    }                                                                         \
    _Pragma("unroll")                                                         \
    for (int q = 0; q < 4; ++q) {                                             \
        const float av = an[((jjb) + q) * 16 + jg];                           \
        acc0 = fmaf(av * wp[q].x, xp[q].x, acc0);                             \
        acc1 = fmaf(av * wp[q].y, xp[q].y, acc1);                             \
        acc2 = fmaf(av * wp[q].z, xp[q].z, acc2);                             \
        acc3 = fmaf(av * wp[q].w, xp[q].w, acc3);                             \
    }

    v4f wA[4], xA[4];
    v4f wB[4], xB[4];

    LOADG(wA, xA, 0)          // group 0: jj 0..3
    LOADG(wB, xB, 1024)       // group 1: jj 4..7   (in flight behind group 0)
    USEG (wA, xA, 0, 0)
    LOADG(wA, xA, 2048)       // group 2: jj 8..11
    USEG (wB, xB, 1024, 4)
    LOADG(wB, xB, 3072)       // group 3: jj 12..15
    USEG (wA, xA, 2048, 8)
    USEG (wB, xB, 3072, 12)

#undef LOADG
#undef USEG

    // ---- reduce over the 16 j-groups ----
    red[tid][0] = acc0; red[tid][1] = acc1;
    red[tid][2] = acc2; red[tid][3] = acc3;
    __syncthreads();

    if (tid < 64) {
        const int c = tid >> 2;      // feature quad
        const int r = tid & 3;       // feature = c*4+r = tid
        float sum = 0.0f;
#pragma unroll
        for (int g = 0; g < 16; ++g) sum += red[g * 16 + c][r];  // 2-way bank alias, free
        sum += sout[row * FF + tid];
        outx2[row * FF + tid] = sum;
    }
}

extern "C" void kernel_launch(void* const* d_in, const int* in_sizes, int n_in,
                              void* d_out, int out_size, void* d_ws, size_t ws_size,
                              hipStream_t stream) {
    const float* A   = (const float*)d_in[0];
    const float* W   = (const float*)d_in[1];
    const float* x   = (const float*)d_in[2];
    const float* nw1 = (const float*)d_in[3];
    const float* nb1 = (const float*)d_in[4];
    const float* nw2 = (const float*)d_in[5];
    const float* nb2 = (const float*)d_in[6];
    const float* sw1 = (const float*)d_in[7];
    const float* sb1 = (const float*)d_in[8];
    const float* sw2 = (const float*)d_in[9];
    const float* sb2 = (const float*)d_in[10];

    float* x1 = (float*)d_ws;                  // 2048*64 fp32 = 512 KB
    float* so = x1 + BROWS * FF;               // + 512 KB

    float* outW  = (float*)d_out;
    float* outx2 = outW + W_ELEMS;

    mlp_kernel<<<BROWS, 64, 0, stream>>>(x, nw1, nb1, nw2, nb2,
                                         sw1, sb1, sw2, sb2, x1, so);
    agg_kernel<<<BROWS, 256, 0, stream>>>(A, W, x1, so, outW, outx2);
}